// Round 4
// baseline (518.556 us; speedup 1.0000x reference)
//
#include <hip/hip_runtime.h>
#include <hip/hip_bf16.h>

#define BB 64
#define SS 4096
#define EE 128   // EMB_DIM
#define DD 128   // DEC_DIM
#define FAN 256
#define NEG_INF_F (-1e10f)

typedef __bf16 bf16x8 __attribute__((ext_vector_type(8)));
typedef unsigned short u16x8 __attribute__((ext_vector_type(8)));
typedef float f32x4 __attribute__((ext_vector_type(4)));

__device__ inline bf16x8 ld_frag(const unsigned short* p) {
    union { u16x8 u; bf16x8 b; } c;
    c.u = *(const u16x8*)p;
    return c.b;
}

__device__ inline uint2 f4_to_bf4(float4 f) {
    union { __hip_bfloat162 b; unsigned u; } lo, hi;
    lo.b = __float22bfloat162_rn(make_float2(f.x, f.y));
    hi.b = __float22bfloat162_rn(make_float2(f.z, f.w));
    return make_uint2(lo.u, hi.u);
}

__device__ inline float tanh_fast(float x) {
    float ax = fabsf(x);
    float e = __expf(-2.0f * ax);
    float t = (1.0f - e) * __builtin_amdgcn_rcpf(1.0f + e);
    return x < 0.0f ? -t : t;
}

// ---------------------------------------------------------------------------
// Kernel 1: h_proj (fp32) + We -> bf16 conversion + v copy, into workspace.
// grid 64 x 256
// ---------------------------------------------------------------------------
__global__ __launch_bounds__(256) void prep_kernel(
        const float* __restrict__ hidden, const float* __restrict__ W_attn,
        const float* __restrict__ b_attn, const float* __restrict__ v_w,
        float* __restrict__ hproj, unsigned short* __restrict__ Wb,
        float* __restrict__ v_out) {
    const int b = blockIdx.x;
    const int t = threadIdx.x;
    if (t < 128) {
        float acc = b_attn[t];
        const float* hrow = hidden + b * DD;
        const float* wrow = W_attn + t * FAN;
        #pragma unroll 8
        for (int e = 0; e < DD; e++) acc += hrow[e] * wrow[e];
        hproj[b * DD + t] = acc;
        if (b == 0) v_out[t] = v_w[t];
    } else {
        int tt = t - 128;
        int d  = 2 * b + (tt >> 6);
        int e0 = (tt & 63) * 2;
        float2 src = *(const float2*)(W_attn + d * FAN + DD + e0);
        union { __hip_bfloat162 bb; unsigned u; } c;
        c.bb = __float22bfloat162_rn(src);
        *(unsigned*)&Wb[d * EE + e0] = c.u;
    }
}

// ---------------------------------------------------------------------------
// Kernel 2 (fused): logits + atomic-tail softmax.
// grid (S/64, B) x 256. Per b-row the LAST finishing block (device-scope
// counter) runs the row softmax in place. Release/acquire fences handle
// cross-XCD L2 non-coherence.
// ---------------------------------------------------------------------------
__global__ __launch_bounds__(256) void logits_softmax_kernel(
        const float* __restrict__ seq_embs, const int* __restrict__ mask,
        const float* __restrict__ hproj, const unsigned short* __restrict__ Wb,
        const float* __restrict__ v, float* __restrict__ logits,
        int* __restrict__ cnt) {
    __shared__ __attribute__((aligned(16))) unsigned short Ws[128][136]; // d x e, pad->conflict-free
    __shared__ float smax[4], ssum[4];
    __shared__ int is_last;

    const int b    = blockIdx.y;
    const int s0   = blockIdx.x * 64;
    const int tid  = threadIdx.x;
    const int wave = tid >> 6;
    const int lane = tid & 63;
    const int m    = lane & 15;
    const int quad = lane >> 4;

    const int* __restrict__ mask_g = mask + (size_t)b * SS + s0;

    // --- A-frags direct from global, fp32->bf16 in-register; masked rows -> 0.
    const int arow = wave * 16 + m;
    const int am   = mask_g[arow];
    const float* xrow = seq_embs + (size_t)(s0 + arow) * (BB * EE)
                      + (size_t)b * EE + quad * 8;
    bf16x8 afrag[4];
    #pragma unroll
    for (int kk = 0; kk < 4; kk++) {
        union { uint4 q; bf16x8 bf; } c;
        c.q = make_uint4(0u, 0u, 0u, 0u);
        if (am != 0) {
            float4 f0 = *(const float4*)(xrow + kk * 32);
            float4 f1 = *(const float4*)(xrow + kk * 32 + 4);
            uint2 a = f4_to_bf4(f0), bq = f4_to_bf4(f1);
            c.q = make_uint4(a.x, a.y, bq.x, bq.y);
        }
        afrag[kk] = c.bf;
    }

    // --- Stage We (bf16, L2-resident ws) into LDS: 16B per thread-iter.
    const uint4* __restrict__ Wb16 = (const uint4*)Wb;
    #pragma unroll
    for (int k = 0; k < 8; k++) {
        const int i = tid + k * 256;
        const int d = i >> 4, e8 = i & 15;
        *(uint4*)&Ws[d][e8 * 8] = Wb16[i];
    }
    __syncthreads();

    // --- MFMA: 64 s-rows x 128 d, K=128
    f32x4 acc[8];
    #pragma unroll
    for (int t = 0; t < 8; t++) acc[t] = (f32x4){0.f, 0.f, 0.f, 0.f};
    #pragma unroll
    for (int kk = 0; kk < 4; kk++) {
        const int k0 = kk * 32 + quad * 8;
        #pragma unroll
        for (int t = 0; t < 8; t++) {
            bf16x8 bf = ld_frag(&Ws[t * 16 + m][k0]);
            acc[t] = __builtin_amdgcn_mfma_f32_16x16x32_bf16(afrag[kk], bf, acc[t], 0, 0, 0);
        }
    }

    // --- Epilogue: logit[s] = sum_d v[d] * tanh(hp[d] + E[s][d])
    float hp_r[8], v_r[8];
    #pragma unroll
    for (int t = 0; t < 8; t++) {
        hp_r[t] = hproj[b * DD + t * 16 + m];
        v_r[t]  = v[t * 16 + m];
    }
    const int4 mq = *(const int4*)(mask_g + wave * 16 + quad * 4);
    const int mqa[4] = {mq.x, mq.y, mq.z, mq.w};

    float red[4];
    #pragma unroll
    for (int r = 0; r < 4; r++) {
        float part = 0.f;
        if (mqa[r] != 0) {   // uniform across the 16-lane m-group: shfl-safe
            #pragma unroll
            for (int t = 0; t < 8; t++)
                part += v_r[t] * tanh_fast(hp_r[t] + acc[t][r]);
            part += __shfl_xor(part, 1);
            part += __shfl_xor(part, 2);
            part += __shfl_xor(part, 4);
            part += __shfl_xor(part, 8);
        }
        red[r] = (mqa[r] != 0) ? part : NEG_INF_F;
    }
    if (m == 0) {
        float4 o = make_float4(red[0], red[1], red[2], red[3]);
        *(float4*)&logits[(size_t)b * SS + s0 + wave * 16 + quad * 4] = o;
    }

    // --- Atomic tail: last block of this b-row runs the softmax.
    __syncthreads();            // all stores of this block complete (vmcnt drained)
    if (tid == 0) {
        __threadfence();        // release: write back dirty L2 (logits) to device
        int prev = __hip_atomic_fetch_add(&cnt[b], 1, __ATOMIC_ACQ_REL,
                                          __HIP_MEMORY_SCOPE_AGENT);
        is_last = (prev == 63) ? 1 : 0;
    }
    __syncthreads();
    if (!is_last) return;
    __threadfence();            // acquire: invalidate stale L1/L2 before re-read

    float* row = logits + (size_t)b * SS;
    float4 vals[4];
    float lmax = -1e30f;
    #pragma unroll
    for (int i = 0; i < 4; i++) {
        vals[i] = *(const float4*)(row + (size_t)(i * 256 + tid) * 4);
        lmax = fmaxf(lmax, fmaxf(fmaxf(vals[i].x, vals[i].y), fmaxf(vals[i].z, vals[i].w)));
    }
    #pragma unroll
    for (int off = 32; off >= 1; off >>= 1)
        lmax = fmaxf(lmax, __shfl_xor(lmax, off));
    if (lane == 0) smax[wave] = lmax;
    __syncthreads();
    const float gmax = fmaxf(fmaxf(smax[0], smax[1]), fmaxf(smax[2], smax[3]));

    float lsum = 0.f;
    #pragma unroll
    for (int i = 0; i < 4; i++) {
        vals[i].x = __expf(vals[i].x - gmax);
        vals[i].y = __expf(vals[i].y - gmax);
        vals[i].z = __expf(vals[i].z - gmax);
        vals[i].w = __expf(vals[i].w - gmax);
        lsum += (vals[i].x + vals[i].y) + (vals[i].z + vals[i].w);
    }
    #pragma unroll
    for (int off = 32; off >= 1; off >>= 1)
        lsum += __shfl_xor(lsum, off);
    if (lane == 0) ssum[wave] = lsum;
    __syncthreads();
    const float total = (ssum[0] + ssum[1]) + (ssum[2] + ssum[3]);
    const float inv = 1.0f / total;

    #pragma unroll
    for (int i = 0; i < 4; i++) {
        float4 o;
        o.x = vals[i].x * inv; o.y = vals[i].y * inv;
        o.z = vals[i].z * inv; o.w = vals[i].w * inv;
        *(float4*)(row + (size_t)(i * 256 + tid) * 4) = o;
    }
}

extern "C" void kernel_launch(void* const* d_in, const int* in_sizes, int n_in,
                              void* d_out, int out_size, void* d_ws, size_t ws_size,
                              hipStream_t stream) {
    const float* hidden   = (const float*)d_in[0];
    const float* seq_embs = (const float*)d_in[1];
    const int*   mask     = (const int*)d_in[2];
    const float* W_attn   = (const float*)d_in[3];
    const float* b_attn   = (const float*)d_in[4];
    const float* v_w      = (const float*)d_in[5];
    float* out = (float*)d_out;

    float*          hproj = (float*)d_ws;                              // 32 KB
    unsigned short* Wb    = (unsigned short*)((char*)d_ws + 32768);    // 32 KB
    float*          vv    = (float*)((char*)d_ws + 65536);             // 512 B
    int*            cnt   = (int*)((char*)d_ws + 66560);               // 256 B

    hipMemsetAsync(cnt, 0, 64 * sizeof(int), stream);
    prep_kernel<<<64, 256, 0, stream>>>(hidden, W_attn, b_attn, v_w, hproj, Wb, vv);
    dim3 grid(SS / 64, BB);
    logits_softmax_kernel<<<grid, 256, 0, stream>>>(seq_embs, mask, hproj, Wb, vv, out, cnt);
}

// Round 5
// 217.887 us; speedup vs baseline: 2.3799x; 2.3799x over previous
//
#include <hip/hip_runtime.h>
#include <hip/hip_bf16.h>

#define BB 64
#define SS 4096
#define EE 128   // EMB_DIM
#define DD 128   // DEC_DIM
#define FAN 256
#define NEG_INF_F (-1e10f)

typedef __bf16 bf16x8 __attribute__((ext_vector_type(8)));
typedef unsigned short u16x8 __attribute__((ext_vector_type(8)));
typedef float f32x4 __attribute__((ext_vector_type(4)));

__device__ inline bf16x8 ld_frag(const unsigned short* p) {
    union { u16x8 u; bf16x8 b; } c;
    c.u = *(const u16x8*)p;
    return c.b;
}

__device__ inline uint2 f4_to_bf4(float4 f) {
    union { __hip_bfloat162 b; unsigned u; } lo, hi;
    lo.b = __float22bfloat162_rn(make_float2(f.x, f.y));
    hi.b = __float22bfloat162_rn(make_float2(f.z, f.w));
    return make_uint2(lo.u, hi.u);
}

__device__ inline float tanh_fast(float x) {
    float ax = fabsf(x);
    float e = __expf(-2.0f * ax);
    float t = (1.0f - e) * __builtin_amdgcn_rcpf(1.0f + e);
    return x < 0.0f ? -t : t;
}

// ---------------------------------------------------------------------------
// Kernel 1: h_proj (fp32) + We -> bf16 conversion + v copy, into workspace.
// grid 64 x 256
// ---------------------------------------------------------------------------
__global__ __launch_bounds__(256) void prep_kernel(
        const float* __restrict__ hidden, const float* __restrict__ W_attn,
        const float* __restrict__ b_attn, const float* __restrict__ v_w,
        float* __restrict__ hproj, unsigned short* __restrict__ Wb,
        float* __restrict__ v_out) {
    const int b = blockIdx.x;
    const int t = threadIdx.x;
    if (t < 128) {
        float acc = b_attn[t];
        const float* hrow = hidden + b * DD;
        const float* wrow = W_attn + t * FAN;
        #pragma unroll 8
        for (int e = 0; e < DD; e++) acc += hrow[e] * wrow[e];
        hproj[b * DD + t] = acc;
        if (b == 0) v_out[t] = v_w[t];
    } else {
        int tt = t - 128;
        int d  = 2 * b + (tt >> 6);
        int e0 = (tt & 63) * 2;
        float2 src = *(const float2*)(W_attn + d * FAN + DD + e0);
        union { __hip_bfloat162 bb; unsigned u; } c;
        c.bb = __float22bfloat162_rn(src);
        *(unsigned*)&Wb[d * EE + e0] = c.u;
    }
}

// ---------------------------------------------------------------------------
// Kernel 2: logits[b][s] = v . tanh(hproj[b] + X[s] @ We^T), masked.
// grid (S/64, B) x 256. Masked s-rows: HBM read skipped via exec mask.
// A-frags loaded global->register directly (no X LDS tile); only Ws in LDS.
// Wb staging issued FIRST so the pre-barrier waitcnt leaves A-loads in flight.
// ---------------------------------------------------------------------------
__global__ __launch_bounds__(256) void logits_kernel(
        const float* __restrict__ seq_embs, const int* __restrict__ mask,
        const float* __restrict__ hproj, const unsigned short* __restrict__ Wb,
        const float* __restrict__ v, float* __restrict__ logits) {
    __shared__ __attribute__((aligned(16))) unsigned short Ws[128][136]; // d x e, pad

    const int b    = blockIdx.y;
    const int s0   = blockIdx.x * 64;
    const int tid  = threadIdx.x;
    const int wave = tid >> 6;
    const int lane = tid & 63;
    const int m    = lane & 15;
    const int quad = lane >> 4;

    const int* __restrict__ mask_g = mask + (size_t)b * SS + s0;

    // --- Stage We (bf16, L2-resident ws): issue these loads first.
    const uint4* __restrict__ Wb16 = (const uint4*)Wb;
    uint4 wstage[8];
    #pragma unroll
    for (int k = 0; k < 8; k++) wstage[k] = Wb16[tid + k * 256];

    // --- A-frags direct from global, fp32->bf16 in-register; masked rows -> 0.
    // A layout: lane(m,quad) holds A[m][quad*8 + j] per K=32 slice kk.
    const int arow = wave * 16 + m;
    const int am   = mask_g[arow];
    const float* xrow = seq_embs + (size_t)(s0 + arow) * (BB * EE)
                      + (size_t)b * EE + quad * 8;
    bf16x8 afrag[4];
    #pragma unroll
    for (int kk = 0; kk < 4; kk++) {
        union { uint4 q; bf16x8 bf; } c;
        c.q = make_uint4(0u, 0u, 0u, 0u);
        if (am != 0) {
            float4 f0 = *(const float4*)(xrow + kk * 32);
            float4 f1 = *(const float4*)(xrow + kk * 32 + 4);
            uint2 a = f4_to_bf4(f0), bq = f4_to_bf4(f1);
            c.q = make_uint4(a.x, a.y, bq.x, bq.y);
        }
        afrag[kk] = c.bf;
    }

    // --- Write staged We into LDS (only these writes gate the barrier).
    #pragma unroll
    for (int k = 0; k < 8; k++) {
        const int i = tid + k * 256;
        const int d = i >> 4, e8 = i & 15;
        *(uint4*)&Ws[d][e8 * 8] = wstage[k];
    }
    __syncthreads();

    // --- MFMA: 64 s-rows x 128 d, K=128
    f32x4 acc[8];
    #pragma unroll
    for (int t = 0; t < 8; t++) acc[t] = (f32x4){0.f, 0.f, 0.f, 0.f};
    #pragma unroll
    for (int kk = 0; kk < 4; kk++) {
        const int k0 = kk * 32 + quad * 8;
        #pragma unroll
        for (int t = 0; t < 8; t++) {
            bf16x8 bf = ld_frag(&Ws[t * 16 + m][k0]);
            acc[t] = __builtin_amdgcn_mfma_f32_16x16x32_bf16(afrag[kk], bf, acc[t], 0, 0, 0);
        }
    }

    // --- Epilogue: logit[s] = sum_d v[d] * tanh(hp[d] + E[s][d])
    // D layout: row = quad*4 + r (s within wave tile), col = m (d within 16-tile)
    float hp_r[8], v_r[8];
    #pragma unroll
    for (int t = 0; t < 8; t++) {
        hp_r[t] = hproj[b * DD + t * 16 + m];
        v_r[t]  = v[t * 16 + m];
    }
    const int4 mq = *(const int4*)(mask_g + wave * 16 + quad * 4);
    const int mqa[4] = {mq.x, mq.y, mq.z, mq.w};

    float red[4];
    #pragma unroll
    for (int r = 0; r < 4; r++) {
        float part = 0.f;
        if (mqa[r] != 0) {   // uniform across the 16-lane m-group: shfl-safe
            #pragma unroll
            for (int t = 0; t < 8; t++)
                part += v_r[t] * tanh_fast(hp_r[t] + acc[t][r]);
            part += __shfl_xor(part, 1);
            part += __shfl_xor(part, 2);
            part += __shfl_xor(part, 4);
            part += __shfl_xor(part, 8);
        }
        red[r] = (mqa[r] != 0) ? part : NEG_INF_F;
    }
    if (m == 0) {
        float4 o = make_float4(red[0], red[1], red[2], red[3]);
        *(float4*)&logits[(size_t)b * SS + s0 + wave * 16 + quad * 4] = o;
    }
}

// ---------------------------------------------------------------------------
// Kernel 3: in-place row softmax over S=4096. grid B x 256.
// ---------------------------------------------------------------------------
__global__ __launch_bounds__(256) void softmax_kernel(float* __restrict__ logits) {
    const int b = blockIdx.x;
    const int tid = threadIdx.x;
    const int wave = tid >> 6;
    const int lane = tid & 63;
    float* row = logits + (size_t)b * SS;

    float4 vals[4];
    float lmax = -1e30f;
    #pragma unroll
    for (int i = 0; i < 4; i++) {
        vals[i] = *(const float4*)(row + (size_t)(i * 256 + tid) * 4);
        lmax = fmaxf(lmax, fmaxf(fmaxf(vals[i].x, vals[i].y), fmaxf(vals[i].z, vals[i].w)));
    }
    #pragma unroll
    for (int off = 32; off >= 1; off >>= 1)
        lmax = fmaxf(lmax, __shfl_xor(lmax, off));

    __shared__ float smax[4], ssum[4];
    if (lane == 0) smax[wave] = lmax;
    __syncthreads();
    const float gmax = fmaxf(fmaxf(smax[0], smax[1]), fmaxf(smax[2], smax[3]));

    float lsum = 0.f;
    #pragma unroll
    for (int i = 0; i < 4; i++) {
        vals[i].x = __expf(vals[i].x - gmax);
        vals[i].y = __expf(vals[i].y - gmax);
        vals[i].z = __expf(vals[i].z - gmax);
        vals[i].w = __expf(vals[i].w - gmax);
        lsum += (vals[i].x + vals[i].y) + (vals[i].z + vals[i].w);
    }
    #pragma unroll
    for (int off = 32; off >= 1; off >>= 1)
        lsum += __shfl_xor(lsum, off);
    if (lane == 0) ssum[wave] = lsum;
    __syncthreads();
    const float total = (ssum[0] + ssum[1]) + (ssum[2] + ssum[3]);
    const float inv = 1.0f / total;

    #pragma unroll
    for (int i = 0; i < 4; i++) {
        float4 o;
        o.x = vals[i].x * inv; o.y = vals[i].y * inv;
        o.z = vals[i].z * inv; o.w = vals[i].w * inv;
        *(float4*)(row + (size_t)(i * 256 + tid) * 4) = o;
    }
}

extern "C" void kernel_launch(void* const* d_in, const int* in_sizes, int n_in,
                              void* d_out, int out_size, void* d_ws, size_t ws_size,
                              hipStream_t stream) {
    const float* hidden   = (const float*)d_in[0];
    const float* seq_embs = (const float*)d_in[1];
    const int*   mask     = (const int*)d_in[2];
    const float* W_attn   = (const float*)d_in[3];
    const float* b_attn   = (const float*)d_in[4];
    const float* v_w      = (const float*)d_in[5];
    float* out = (float*)d_out;

    float*          hproj = (float*)d_ws;                              // 32 KB
    unsigned short* Wb    = (unsigned short*)((char*)d_ws + 32768);    // 32 KB
    float*          vv    = (float*)((char*)d_ws + 65536);             // 512 B

    prep_kernel<<<64, 256, 0, stream>>>(hidden, W_attn, b_attn, v_w, hproj, Wb, vv);
    dim3 grid(SS / 64, BB);
    logits_kernel<<<grid, 256, 0, stream>>>(seq_embs, mask, hproj, Wb, vv, out);
    softmax_kernel<<<BB, 256, 0, stream>>>(out);
}

// Round 7
// 212.844 us; speedup vs baseline: 2.4363x; 1.0237x over previous
//
#include <hip/hip_runtime.h>
#include <hip/hip_bf16.h>

#define BB 64
#define SS 4096
#define EE 128   // EMB_DIM
#define DD 128   // DEC_DIM
#define FAN 256
#define TILES 4  // s-tiles (64 rows each) per logits block
#define NEG_INF_F (-1e10f)

typedef __bf16 bf16x8 __attribute__((ext_vector_type(8)));
typedef unsigned short u16x8 __attribute__((ext_vector_type(8)));
typedef float f32x4 __attribute__((ext_vector_type(4)));

__device__ inline bf16x8 ld_frag(const unsigned short* p) {
    union { u16x8 u; bf16x8 b; } c;
    c.u = *(const u16x8*)p;
    return c.b;
}

__device__ inline uint2 f4_to_bf4(float4 f) {
    union { __hip_bfloat162 b; unsigned u; } lo, hi;
    lo.b = __float22bfloat162_rn(make_float2(f.x, f.y));
    hi.b = __float22bfloat162_rn(make_float2(f.z, f.w));
    return make_uint2(lo.u, hi.u);
}

__device__ inline float tanh_fast(float x) {
    float ax = fabsf(x);
    float e = __expf(-2.0f * ax);
    float t = (1.0f - e) * __builtin_amdgcn_rcpf(1.0f + e);
    return x < 0.0f ? -t : t;
}

// ---------------------------------------------------------------------------
// Kernel 1: h_proj (fp32) + We -> bf16 conversion + v copy, into workspace.
// grid 64 x 256
// ---------------------------------------------------------------------------
__global__ __launch_bounds__(256) void prep_kernel(
        const float* __restrict__ hidden, const float* __restrict__ W_attn,
        const float* __restrict__ b_attn, const float* __restrict__ v_w,
        float* __restrict__ hproj, unsigned short* __restrict__ Wb,
        float* __restrict__ v_out) {
    const int b = blockIdx.x;
    const int t = threadIdx.x;
    if (t < 128) {
        float acc = b_attn[t];
        const float4* hrow = (const float4*)(hidden + b * DD);
        const float4* wrow = (const float4*)(W_attn + t * FAN);
        #pragma unroll
        for (int e = 0; e < 32; e++) {
            float4 h = hrow[e], w = wrow[e];
            acc += h.x * w.x + h.y * w.y + h.z * w.z + h.w * w.w;
        }
        hproj[b * DD + t] = acc;
        if (b == 0) v_out[t] = v_w[t];
    } else {
        int tt = t - 128;
        int d  = 2 * b + (tt >> 6);
        int e0 = (tt & 63) * 2;
        float2 src = *(const float2*)(W_attn + d * FAN + DD + e0);
        union { __hip_bfloat162 bb; unsigned u; } c;
        c.bb = __float22bfloat162_rn(src);
        *(unsigned*)&Wb[d * EE + e0] = c.u;
    }
}

// ---------------------------------------------------------------------------
// Kernel 2: logits[b][s] = v . tanh(hproj[b] + X[s] @ We^T), masked.
// grid (16, 64) x 256: each block stages Ws ONCE (one barrier) then loops
// over 4 s-tiles of 64 rows with double-buffered A-frag prefetch.
// FIX vs R6: xbase includes this lane's own A-row (arow * BB*EE).
// ---------------------------------------------------------------------------
__global__ __launch_bounds__(256, 4) void logits_kernel(
        const float* __restrict__ seq_embs, const int* __restrict__ mask,
        const float* __restrict__ hproj, const unsigned short* __restrict__ Wb,
        const float* __restrict__ v, float* __restrict__ logits) {
    __shared__ __attribute__((aligned(16))) unsigned short Ws[128][136]; // d x e, pad

    const int b    = blockIdx.y;
    const int g    = blockIdx.x;          // tile group: s rows [g*256, g*256+255]
    const int tid  = threadIdx.x;
    const int wave = tid >> 6;
    const int lane = tid & 63;
    const int m    = lane & 15;
    const int quad = lane >> 4;

    const int arow = wave * 16 + m;       // this lane's s-row within each tile

    const int* __restrict__ mask_g = mask + (size_t)b * SS + g * (TILES * 64);
    const float* __restrict__ xbase = seq_embs
        + (size_t)(g * (TILES * 64) + arow) * (BB * EE)   // <-- FIX: + arow
        + (size_t)b * EE + quad * 8;

    // --- Stage We (bf16, L2-resident ws) into LDS once.
    const uint4* __restrict__ Wb16 = (const uint4*)Wb;
    uint4 wstage[8];
    #pragma unroll
    for (int k = 0; k < 8; k++) wstage[k] = Wb16[tid + k * 256];
    #pragma unroll
    for (int k = 0; k < 8; k++) {
        const int i = tid + k * 256;
        *(uint4*)&Ws[i >> 4][(i & 15) * 8] = wstage[k];
    }

    // --- Prefetch tile 0's A-frags while the barrier drains.
    int am[2];
    int4 mq[2];
    bf16x8 af[2][4];
    {
        am[0] = mask_g[arow];
        mq[0] = *(const int4*)(mask_g + wave * 16 + quad * 4);
        const float* xrow = xbase;
        #pragma unroll
        for (int kk = 0; kk < 4; kk++) {
            union { uint4 q; bf16x8 bf; } c;
            c.q = make_uint4(0u, 0u, 0u, 0u);
            if (am[0] != 0) {
                float4 f0 = *(const float4*)(xrow + kk * 32);
                float4 f1 = *(const float4*)(xrow + kk * 32 + 4);
                uint2 a = f4_to_bf4(f0), bq = f4_to_bf4(f1);
                c.q = make_uint4(a.x, a.y, bq.x, bq.y);
            }
            af[0][kk] = c.bf;
        }
    }
    __syncthreads();

    // --- Per-lane epilogue constants.
    float hp_r[8], v_r[8];
    #pragma unroll
    for (int t = 0; t < 8; t++) {
        hp_r[t] = hproj[b * DD + t * 16 + m];
        v_r[t]  = v[t * 16 + m];
    }

    #pragma unroll
    for (int tile = 0; tile < TILES; tile++) {
        const int cur = tile & 1;
        // Prefetch next tile's mask + A-frags (independent of this tile's MFMA).
        if (tile + 1 < TILES) {
            const int nxt = cur ^ 1;
            am[nxt] = mask_g[(tile + 1) * 64 + arow];
            mq[nxt] = *(const int4*)(mask_g + (tile + 1) * 64 + wave * 16 + quad * 4);
            const float* xrow = xbase + (size_t)((tile + 1) * 64) * (BB * EE);
            #pragma unroll
            for (int kk = 0; kk < 4; kk++) {
                union { uint4 q; bf16x8 bf; } c;
                c.q = make_uint4(0u, 0u, 0u, 0u);
                if (am[nxt] != 0) {
                    float4 f0 = *(const float4*)(xrow + kk * 32);
                    float4 f1 = *(const float4*)(xrow + kk * 32 + 4);
                    uint2 a = f4_to_bf4(f0), bq = f4_to_bf4(f1);
                    c.q = make_uint4(a.x, a.y, bq.x, bq.y);
                }
                af[nxt][kk] = c.bf;
            }
        }

        // --- MFMA: 64 s-rows x 128 d, K=128
        f32x4 acc[8];
        #pragma unroll
        for (int t = 0; t < 8; t++) acc[t] = (f32x4){0.f, 0.f, 0.f, 0.f};
        #pragma unroll
        for (int kk = 0; kk < 4; kk++) {
            const int k0 = kk * 32 + quad * 8;
            #pragma unroll
            for (int t = 0; t < 8; t++) {
                bf16x8 bf = ld_frag(&Ws[t * 16 + m][k0]);
                acc[t] = __builtin_amdgcn_mfma_f32_16x16x32_bf16(af[cur][kk], bf, acc[t], 0, 0, 0);
            }
        }

        // --- Epilogue: logit[s] = sum_d v[d] * tanh(hp[d] + E[s][d])
        const int mqa[4] = {mq[cur].x, mq[cur].y, mq[cur].z, mq[cur].w};
        float red[4];
        #pragma unroll
        for (int r = 0; r < 4; r++) {
            float part = 0.f;
            if (mqa[r] != 0) {   // uniform across the 16-lane m-group: shfl-safe
                #pragma unroll
                for (int t = 0; t < 8; t++)
                    part += v_r[t] * tanh_fast(hp_r[t] + acc[t][r]);
                part += __shfl_xor(part, 1);
                part += __shfl_xor(part, 2);
                part += __shfl_xor(part, 4);
                part += __shfl_xor(part, 8);
            }
            red[r] = (mqa[r] != 0) ? part : NEG_INF_F;
        }
        if (m == 0) {
            float4 o = make_float4(red[0], red[1], red[2], red[3]);
            *(float4*)&logits[(size_t)b * SS + g * (TILES * 64) + tile * 64
                              + wave * 16 + quad * 4] = o;
        }
    }
}

// ---------------------------------------------------------------------------
// Kernel 3: in-place row softmax over S=4096. grid B x 256.
// ---------------------------------------------------------------------------
__global__ __launch_bounds__(256) void softmax_kernel(float* __restrict__ logits) {
    const int b = blockIdx.x;
    const int tid = threadIdx.x;
    const int wave = tid >> 6;
    const int lane = tid & 63;
    float* row = logits + (size_t)b * SS;

    float4 vals[4];
    float lmax = -1e30f;
    #pragma unroll
    for (int i = 0; i < 4; i++) {
        vals[i] = *(const float4*)(row + (size_t)(i * 256 + tid) * 4);
        lmax = fmaxf(lmax, fmaxf(fmaxf(vals[i].x, vals[i].y), fmaxf(vals[i].z, vals[i].w)));
    }
    #pragma unroll
    for (int off = 32; off >= 1; off >>= 1)
        lmax = fmaxf(lmax, __shfl_xor(lmax, off));

    __shared__ float smax[4], ssum[4];
    if (lane == 0) smax[wave] = lmax;
    __syncthreads();
    const float gmax = fmaxf(fmaxf(smax[0], smax[1]), fmaxf(smax[2], smax[3]));

    float lsum = 0.f;
    #pragma unroll
    for (int i = 0; i < 4; i++) {
        vals[i].x = __expf(vals[i].x - gmax);
        vals[i].y = __expf(vals[i].y - gmax);
        vals[i].z = __expf(vals[i].z - gmax);
        vals[i].w = __expf(vals[i].w - gmax);
        lsum += (vals[i].x + vals[i].y) + (vals[i].z + vals[i].w);
    }
    #pragma unroll
    for (int off = 32; off >= 1; off >>= 1)
        lsum += __shfl_xor(lsum, off);
    if (lane == 0) ssum[wave] = lsum;
    __syncthreads();
    const float total = (ssum[0] + ssum[1]) + (ssum[2] + ssum[3]);
    const float inv = 1.0f / total;

    #pragma unroll
    for (int i = 0; i < 4; i++) {
        float4 o;
        o.x = vals[i].x * inv; o.y = vals[i].y * inv;
        o.z = vals[i].z * inv; o.w = vals[i].w * inv;
        *(float4*)(row + (size_t)(i * 256 + tid) * 4) = o;
    }
}

extern "C" void kernel_launch(void* const* d_in, const int* in_sizes, int n_in,
                              void* d_out, int out_size, void* d_ws, size_t ws_size,
                              hipStream_t stream) {
    const float* hidden   = (const float*)d_in[0];
    const float* seq_embs = (const float*)d_in[1];
    const int*   mask     = (const int*)d_in[2];
    const float* W_attn   = (const float*)d_in[3];
    const float* b_attn   = (const float*)d_in[4];
    const float* v_w      = (const float*)d_in[5];
    float* out = (float*)d_out;

    float*          hproj = (float*)d_ws;                              // 32 KB
    unsigned short* Wb    = (unsigned short*)((char*)d_ws + 32768);    // 32 KB
    float*          vv    = (float*)((char*)d_ws + 65536);             // 512 B

    prep_kernel<<<64, 256, 0, stream>>>(hidden, W_attn, b_attn, v_w, hproj, Wb, vv);
    dim3 grid(SS / (64 * TILES), BB);
    logits_kernel<<<grid, 256, 0, stream>>>(seq_embs, mask, hproj, Wb, vv, out);
    softmax_kernel<<<BB, 256, 0, stream>>>(out);
}